// Round 5
// baseline (333.102 us; speedup 1.0000x reference)
//
#include <hip/hip_runtime.h>
#include <hip/hip_bf16.h>

typedef __attribute__((ext_vector_type(8))) short bf16x8;
typedef __attribute__((ext_vector_type(4))) float f32x4;
typedef unsigned short ushort_t;

#define HID 2048
#define QKVN 6144
#define SEQ 2048
#define NH 16
#define HD 128
#define QB 128
#define KVB 64

#define GLOBAL_AS __attribute__((address_space(1)))
#define LDS_AS __attribute__((address_space(3)))

__device__ __forceinline__ void gload_lds16(const ushort_t* g, ushort_t* l) {
    __builtin_amdgcn_global_load_lds((const GLOBAL_AS unsigned int*)g,
                                     (LDS_AS unsigned int*)l, 16, 0, 0);
}

__device__ __forceinline__ ushort_t f2b(float f) {
    union { float f; unsigned int u; } x; x.f = f;
    unsigned int r = x.u + 0x7fffu + ((x.u >> 16) & 1u);  // RNE
    return (ushort_t)(r >> 16);
}

#define BARX() asm volatile("s_barrier" ::: "memory")
#define VMC4() asm volatile("s_waitcnt vmcnt(4)" ::: "memory")
#define VMC0() asm volatile("s_waitcnt vmcnt(0)" ::: "memory")

// ---------------- cast fp32 -> bf16 (vectorized) ----------------
__global__ __launch_bounds__(256) void castbf(const float* __restrict__ in,
                                              ushort_t* __restrict__ out, int n) {
    int i = (blockIdx.x * 256 + threadIdx.x) * 8;
    if (i >= n) return;
    float4 a = *(const float4*)(in + i);
    float4 b = *(const float4*)(in + i + 4);
    union { ushort_t u[8]; uint4 v; } r;
    r.u[0] = f2b(a.x); r.u[1] = f2b(a.y); r.u[2] = f2b(a.z); r.u[3] = f2b(a.w);
    r.u[4] = f2b(b.x); r.u[5] = f2b(b.y); r.u[6] = f2b(b.z); r.u[7] = f2b(b.w);
    *(uint4*)(out + i) = r.v;
}

// ------------- transpose + cast: fp32 K x N  ->  bf16 N x K -------------
__global__ __launch_bounds__(256) void transcast(const float* __restrict__ in,
                                                 ushort_t* __restrict__ out,
                                                 int Kd, int Nd) {
    __shared__ float tile[32][33];
    int tx = threadIdx.x & 31, ty = threadIdx.x >> 5;
    int n0 = blockIdx.x * 32, k0 = blockIdx.y * 32;
    for (int j = 0; j < 4; j++)
        tile[ty + 8 * j][tx] = in[(size_t)(k0 + ty + 8 * j) * Nd + n0 + tx];
    __syncthreads();
    for (int j = 0; j < 4; j++)
        out[(size_t)(n0 + ty + 8 * j) * Kd + k0 + tx] = f2b(tile[tx][ty + 8 * j]);
}

// ------------- transpose V region of qkv (bf16) -> vT[b][h][d][s] -------------
__global__ __launch_bounds__(256) void transV(const ushort_t* __restrict__ qkvb,
                                              ushort_t* __restrict__ vT) {
    __shared__ ushort_t tile[32][33];
    int tx = threadIdx.x & 31, ty = threadIdx.x >> 5;
    int s0 = blockIdx.x * 32, d0 = blockIdx.y * 32;
    int bh = blockIdx.z; int b = bh >> 4, h = bh & 15;
    for (int j = 0; j < 4; j++)
        tile[ty + 8 * j][tx] =
            qkvb[(size_t)(b * SEQ + s0 + ty + 8 * j) * QKVN + 2 * HID + h * HD + d0 + tx];
    __syncthreads();
    for (int j = 0; j < 4; j++)
        vT[((size_t)bh * HD + d0 + ty + 8 * j) * SEQ + s0 + tx] = tile[tx][ty + 8 * j];
}

// ------------- GEMM 256x256, 8-phase schedule (T2+T3+T4+T5), BK=64, 8 waves -------------
// C(MxN) = A(MxK,bf16) * BT(NxK,bf16)^T.
// A-sub s: block rows r with bit6(r)==s, index ras = wm*64 + (r&63). B-sub s: block cols c
// with bit5(c)==s, index rbs = wn*32 + (c&31). Quadrant order per K-tile: (0,0),(0,1),(1,1),(1,0).
// Stage slots per iteration (2 K-tiles): ph0: buf1.{A1,B0}(kt 2i+1); ph2: buf0.A0(2i+2);
// ph3: buf0.B1 + vmcnt(4); ph4: buf0.{A1,B0}; ph6: buf1.A0(2i+3); ph7: buf1.B1 + vmcnt(4).
template <bool OUT_BF16>
__global__ __launch_bounds__(512, 1) void gemm8p(const ushort_t* __restrict__ A,
                                                 const ushort_t* __restrict__ BT,
                                                 void* __restrict__ C,
                                                 int M, int N, int K,
                                                 int scale_cols, float scale) {
    __shared__ __align__(16) ushort_t As[2][2][128 * 64];  // 64 KB
    __shared__ __align__(16) ushort_t Bs[2][2][128 * 64];  // 64 KB

    const int t = threadIdx.x;
    const int l = t & 63, w = t >> 6;
    const int wm = w >> 2, wn = w & 3;          // 2 x 4 waves
    const int lr = l & 15, lg = l >> 4;
    const int sw = (lr & 7) << 4;

    // XCD-aware bijective swizzle (grid % 8 == 0 for all our shapes)
    const int nwg = gridDim.x;
    const int cpx = nwg >> 3;
    const int swb = (blockIdx.x & 7) * cpx + (blockIdx.x >> 3);
    const int NTN = N >> 8;
    const int m0 = (swb / NTN) << 8, n0 = (swb % NTN) << 8;

    const int NKT = K >> 6;
    const int NIT = NKT >> 1;

    f32x4 acc[8][4] = {};

#define STAGE_A(BUF, SUB, KT)                                                      \
    do {                                                                           \
        _Pragma("unroll") for (int sx = 0; sx < 2; sx++) {                         \
            const int i_ = sx * 512 + t;                                           \
            const int rs_ = i_ >> 3;                                               \
            const int grow_ = m0 + ((rs_ >> 6) << 7) + ((SUB) << 6) + (rs_ & 63);  \
            const int gcol_ = ((KT) << 6) + (((i_ & 7) ^ (rs_ & 7)) << 3);         \
            gload_lds16(A + (size_t)grow_ * K + gcol_, &As[BUF][SUB][i_ * 8]);     \
        }                                                                          \
    } while (0)
#define STAGE_B(BUF, SUB, KT)                                                      \
    do {                                                                           \
        _Pragma("unroll") for (int sx = 0; sx < 2; sx++) {                         \
            const int i_ = sx * 512 + t;                                           \
            const int rs_ = i_ >> 3;                                               \
            const int grow_ = n0 + ((rs_ >> 5) << 6) + ((SUB) << 5) + (rs_ & 31);  \
            const int gcol_ = ((KT) << 6) + (((i_ & 7) ^ (rs_ & 7)) << 3);         \
            gload_lds16(BT + (size_t)grow_ * K + gcol_, &Bs[BUF][SUB][i_ * 8]);    \
        }                                                                          \
    } while (0)

#define PHASE(BUF, MQ, NQ, STAGES)                                                  \
    {                                                                               \
        bf16x8 af[2][4], bfr[2][2];                                                 \
        const char* aB_ = (const char*)&As[BUF][MQ][0];                             \
        const char* bB_ = (const char*)&Bs[BUF][NQ][0];                             \
        _Pragma("unroll") for (int kk = 0; kk < 2; kk++) {                          \
            _Pragma("unroll") for (int mi = 0; mi < 4; mi++)                        \
                af[kk][mi] = *(const bf16x8*)(aB_ + (wm * 64 + mi * 16 + lr) * 128  \
                                              + ((kk * 64 + lg * 16) ^ sw));        \
            _Pragma("unroll") for (int ni = 0; ni < 2; ni++)                        \
                bfr[kk][ni] = *(const bf16x8*)(bB_ + (wn * 32 + ni * 16 + lr) * 128 \
                                               + ((kk * 64 + lg * 16) ^ sw));       \
        }                                                                           \
        STAGES;                                                                     \
        BARX();                                                                     \
        __builtin_amdgcn_s_setprio(1);                                              \
        _Pragma("unroll") for (int kk = 0; kk < 2; kk++)                            \
            _Pragma("unroll") for (int mi = 0; mi < 4; mi++)                        \
                _Pragma("unroll") for (int ni = 0; ni < 2; ni++)                    \
                    acc[(MQ) * 4 + mi][(NQ) * 2 + ni] =                             \
                        __builtin_amdgcn_mfma_f32_16x16x32_bf16(                    \
                            af[kk][mi], bfr[kk][ni],                                \
                            acc[(MQ) * 4 + mi][(NQ) * 2 + ni], 0, 0, 0);            \
        __builtin_amdgcn_s_setprio(0);                                              \
        BARX();                                                                     \
    }

    // prologue: buf0 all 4 subs (kt0), buf1.{A0,B1} (kt1); wait for buf0 only
    STAGE_A(0, 0, 0); STAGE_B(0, 1, 0); STAGE_A(0, 1, 0); STAGE_B(0, 0, 0);
    STAGE_A(1, 0, 1); STAGE_B(1, 1, 1);
    VMC4();
    BARX();

    for (int it = 0; it < NIT; it++) {
        const int kt1  = 2 * it + 1;
        const int ktn2 = min(2 * it + 2, NKT - 1);   // clamp: tail re-stages dead subs
        const int ktn3 = min(2 * it + 3, NKT - 1);
        PHASE(0, 0, 0, { STAGE_A(1, 1, kt1); STAGE_B(1, 0, kt1); });
        PHASE(0, 0, 1, {});
        PHASE(0, 1, 1, { STAGE_A(0, 0, ktn2); });
        PHASE(0, 1, 0, { STAGE_B(0, 1, ktn2); VMC4(); });
        PHASE(1, 0, 0, { STAGE_A(0, 1, ktn2); STAGE_B(0, 0, ktn2); });
        PHASE(1, 0, 1, {});
        PHASE(1, 1, 1, { STAGE_A(1, 0, ktn3); });
        PHASE(1, 1, 0, { STAGE_B(1, 1, ktn3); VMC4(); });
    }
    VMC0();

#undef PHASE
#undef STAGE_A
#undef STAGE_B

    // epilogue
#pragma unroll
    for (int mq = 0; mq < 2; mq++)
#pragma unroll
        for (int mi = 0; mi < 4; mi++)
#pragma unroll
            for (int nq = 0; nq < 2; nq++)
#pragma unroll
                for (int ni = 0; ni < 2; ni++) {
                    const int row = m0 + wm * 128 + mq * 64 + mi * 16 + lg * 4;
                    const int col = n0 + wn * 64 + nq * 32 + ni * 16 + lr;
                    const float sc = (col < scale_cols) ? scale : 1.0f;
                    const f32x4 v = acc[mq * 4 + mi][nq * 2 + ni];
#pragma unroll
                    for (int j = 0; j < 4; j++) {
                        if (OUT_BF16)
                            ((ushort_t*)C)[(size_t)(row + j) * N + col] = f2b(v[j] * sc);
                        else
                            ((float*)C)[(size_t)(row + j) * N + col] = v[j] * sc;
                    }
                }
}

// ------------- flash attention v3: 8 waves x 16 q-rows, paired q-tiles, dbuf gload_lds -------------
__global__ __launch_bounds__(512, 1) void attn_fwd3(const ushort_t* __restrict__ qkvb,
                                                    const ushort_t* __restrict__ vT,
                                                    ushort_t* __restrict__ attnb) {
    __shared__ __align__(16) ushort_t Ks[2][64 * 128];
    __shared__ __align__(16) ushort_t Vs[2][128 * 64];
    __shared__ __align__(16) ushort_t Ps[8][16 * 64];

    const int t = threadIdx.x;
    const int l = t & 63, w = t >> 6;
    const int lr = l & 15, lg = l >> 4;
    const int pr = blockIdx.x, h = blockIdx.y, b = blockIdx.z;

    const ushort_t* kg = qkvb + (size_t)(b * SEQ) * QKVN + HID + h * HD;
    const ushort_t* vg = vT + (size_t)(b * NH + h) * HD * SEQ;

    char* PsB = (char*)Ps[w];
    const int pssz = ((lr & 7) ^ ((lr >> 3) << 1)) << 4;

    const int kcA = 2 * w, kcB = 2 * w + 1;
    const int krA = 8 * w + (l >> 4), krB = krA + 4;
    const int kcolA = ((l & 15) ^ (l >> 4)) << 3;
    const int kcolB = ((l & 15) ^ (4 + (l >> 4))) << 3;
    const int vrA = 16 * w + (l >> 3), vrB = vrA + 8;
    const int vcol = ((l & 7) ^ (l >> 3)) << 3;

    for (int seg = 0; seg < 2; seg++) {
        const int qt = (seg == 0) ? pr : 15 - pr;
        const int q0 = qt * QB;
        const int q0w = q0 + w * 16;
        const int NT = (q0 + QB) / KVB;

        bf16x8 qf[4];
        {
            const ushort_t* qb = qkvb + (size_t)(b * SEQ + q0w + lr) * QKVN + h * HD + lg * 8;
#pragma unroll
            for (int kc = 0; kc < 4; kc++) qf[kc] = *(const bf16x8*)(qb + kc * 32);
        }
        f32x4 o[8] = {};
        float m[4] = {-3e38f, -3e38f, -3e38f, -3e38f};
        float ls[4] = {0.f, 0.f, 0.f, 0.f};

        __syncthreads();
        gload_lds16(kg + (size_t)krA * QKVN + kcolA, &Ks[0][kcA * 512 + l * 8]);
        gload_lds16(kg + (size_t)krB * QKVN + kcolB, &Ks[0][kcB * 512 + l * 8]);
        gload_lds16(vg + (size_t)vrA * SEQ + vcol,   &Vs[0][kcA * 512 + l * 8]);
        gload_lds16(vg + (size_t)vrB * SEQ + vcol,   &Vs[0][kcB * 512 + l * 8]);

        for (int kt = 0; kt < NT; kt++) {
            const int kv0 = kt * KVB;
            __syncthreads();
            if (kt + 1 < NT) {
                const int nb = (kt + 1) & 1;
                const int nkv = kv0 + KVB;
                gload_lds16(kg + (size_t)(nkv + krA) * QKVN + kcolA, &Ks[nb][kcA * 512 + l * 8]);
                gload_lds16(kg + (size_t)(nkv + krB) * QKVN + kcolB, &Ks[nb][kcB * 512 + l * 8]);
                gload_lds16(vg + (size_t)vrA * SEQ + nkv + vcol,     &Vs[nb][kcA * 512 + l * 8]);
                gload_lds16(vg + (size_t)vrB * SEQ + nkv + vcol,     &Vs[nb][kcB * 512 + l * 8]);
            }
            if (kv0 > q0w + 15) continue;
            const char* KsB = (const char*)Ks[kt & 1];
            const char* VsB = (const char*)Vs[kt & 1];

            f32x4 s[4];
            const int rs = (lr & 7) << 4;
#pragma unroll
            for (int nf = 0; nf < 4; nf++) {
                const int r = nf * 16 + lr;
                s[nf] = (f32x4){0.f, 0.f, 0.f, 0.f};
#pragma unroll
                for (int kc = 0; kc < 4; kc++) {
                    bf16x8 kf = *(const bf16x8*)(KsB + r * 256 + ((kc * 64 + lg * 16) ^ rs));
                    s[nf] = __builtin_amdgcn_mfma_f32_16x16x32_bf16(qf[kc], kf, s[nf], 0, 0, 0);
                }
            }

            const bool diag = (kv0 + 63 > q0w);
            float tm[4];
#pragma unroll
            for (int j = 0; j < 4; j++) {
                if (diag) {
                    const int qpos = q0w + lg * 4 + j;
#pragma unroll
                    for (int nf = 0; nf < 4; nf++)
                        if (kv0 + nf * 16 + lr > qpos) s[nf][j] = -3e38f;
                }
                tm[j] = fmaxf(fmaxf(s[0][j], s[1][j]), fmaxf(s[2][j], s[3][j]));
#pragma unroll
                for (int mk = 1; mk < 16; mk <<= 1)
                    tm[j] = fmaxf(tm[j], __shfl_xor(tm[j], mk, 64));
            }

            float grow = fmaxf(fmaxf(tm[0] - m[0], tm[1] - m[1]),
                               fmaxf(tm[2] - m[2], tm[3] - m[3]));
            if (!__all(grow <= 8.0f)) {
#pragma unroll
                for (int j = 0; j < 4; j++) {
                    const float mn = fmaxf(m[j], tm[j]);
                    const float fac = exp2f((m[j] - mn) * 1.44269504f);
                    m[j] = mn; ls[j] *= fac;
#pragma unroll
                    for (int nf2 = 0; nf2 < 8; nf2++) o[nf2][j] *= fac;
                }
            }

#pragma unroll
            for (int j = 0; j < 4; j++) {
                const int row = lg * 4 + j;
                const int rsz = ((row & 7) ^ ((row >> 3) << 1)) << 4;
                float psum = 0.f;
#pragma unroll
                for (int nf = 0; nf < 4; nf++) {
                    float p = exp2f((s[nf][j] - m[j]) * 1.44269504f);
                    psum += p;
                    union { float f; unsigned u; } cv; cv.f = p;
                    *(ushort_t*)(PsB + row * 128 + ((nf * 32 + lr * 2) ^ rsz)) = (ushort_t)(cv.u >> 16);
                }
                ls[j] += psum;
            }

            bf16x8 pa0 = *(const bf16x8*)(PsB + lr * 128 + ((lg * 16) ^ pssz));
            bf16x8 pa1 = *(const bf16x8*)(PsB + lr * 128 + ((64 + lg * 16) ^ pssz));
#pragma unroll
            for (int nf2 = 0; nf2 < 8; nf2++) {
                const int vr2 = nf2 * 16 + lr;
                bf16x8 vb0 = *(const bf16x8*)(VsB + vr2 * 128 + ((lg * 16) ^ rs));
                bf16x8 vb1 = *(const bf16x8*)(VsB + vr2 * 128 + ((64 + lg * 16) ^ rs));
                o[nf2] = __builtin_amdgcn_mfma_f32_16x16x32_bf16(pa0, vb0, o[nf2], 0, 0, 0);
                o[nf2] = __builtin_amdgcn_mfma_f32_16x16x32_bf16(pa1, vb1, o[nf2], 0, 0, 0);
            }
        }

        float inv[4];
#pragma unroll
        for (int j = 0; j < 4; j++) {
            float sum = ls[j];
#pragma unroll
            for (int mk = 1; mk < 16; mk <<= 1) sum += __shfl_xor(sum, mk, 64);
            inv[j] = 1.0f / sum;
        }
        ushort_t* ob = attnb + (size_t)(b * SEQ + q0w) * HID + h * HD;
#pragma unroll
        for (int nf2 = 0; nf2 < 8; nf2++)
#pragma unroll
            for (int j = 0; j < 4; j++)
                ob[(size_t)(lg * 4 + j) * HID + nf2 * 16 + lr] = f2b(o[nf2][j] * inv[j]);
    }
}

extern "C" void kernel_launch(void* const* d_in, const int* in_sizes, int n_in,
                              void* d_out, int out_size, void* d_ws, size_t ws_size,
                              hipStream_t stream) {
    const float* x     = (const float*)d_in[0];
    const float* w_qkv = (const float*)d_in[1];
    const float* w_out = (const float*)d_in[2];
    float* out = (float*)d_out;

    char* ws = (char*)d_ws;
    ushort_t* xb    = (ushort_t*)(ws);                 // 4096x2048 bf16
    ushort_t* wqkvT = (ushort_t*)(ws + 16777216);      // 6144x2048 bf16
    ushort_t* woutT = (ushort_t*)(ws + 41943040);      // 2048x2048 bf16
    ushort_t* qkvb  = (ushort_t*)(ws + 50331648);      // 4096x6144 bf16
    ushort_t* vT    = (ushort_t*)(ws + 100663296);     // [b][h][d][s] bf16
    ushort_t* attnb = (ushort_t*)(ws + 117440512);     // 4096x2048 bf16

    const int M = 2 * SEQ;  // 4096

    castbf<<<(M * HID) / (256 * 8), 256, 0, stream>>>(x, xb, M * HID);
    transcast<<<dim3(QKVN / 32, HID / 32), 256, 0, stream>>>(w_qkv, wqkvT, HID, QKVN);
    transcast<<<dim3(HID / 32, HID / 32), 256, 0, stream>>>(w_out, woutT, HID, HID);

    // qkv = x @ w_qkv, Q pre-scaled by 1/sqrt(HD); 8-phase 256^2 GEMM
    gemm8p<true><<<(M / 256) * (QKVN / 256), 512, 0, stream>>>(
        xb, wqkvT, qkvb, M, QKVN, HID, HID, 0.08838834764831845f);

    transV<<<dim3(SEQ / 32, HD / 32, 2 * NH), 256, 0, stream>>>(qkvb, vT);

    attn_fwd3<<<dim3(8, NH, 2), 512, 0, stream>>>(qkvb, vT, attnb);

    gemm8p<false><<<(M / 256) * (HID / 256), 512, 0, stream>>>(
        attnb, woutT, out, M, HID, HID, 0, 1.0f);
}